// Round 5
// baseline (361.601 us; speedup 1.0000x reference)
//
#include <hip/hip_runtime.h>
#include <hip/hip_bf16.h>

// Problem: MHA forward, B=2, S=2048, D_MODEL=1024, H=16, Dk=64, causal, RoPE.
// I/O dtype: fp32 (reference dtype; CONFIRMED empirically in R4 — bf16
// misread gave NaN, fp32 read gave finite). Output: fp32. Tolerance is
// bf16-grade (floor_eps_k=8) because compute is expected to use bf16 MFMA.
// Internal: bf16 MFMA 16x16x32, fp32 accum; bf16 intermediates in d_ws.

typedef unsigned short u16;
typedef __attribute__((ext_vector_type(8))) short short8;   // 8 bf16 = 4 VGPRs
typedef __attribute__((ext_vector_type(4))) float float4v;  // MFMA C/D

#define LSTR 72       // LDS row stride (64 + 8 pad): 144B row step -> 2-way bank alias (free)
#define MASKV (-3.0e38f)

__device__ __forceinline__ u16 f2b(float f) {
    union { float f; unsigned int i; } t; t.f = f;
    unsigned int r = t.i + 0x7fffu + ((t.i >> 16) & 1u);   // RNE
    return (u16)(r >> 16);
}

// ---------------------------------------------------------------------------
// Y[m][n] = sum_k X[m][k] * W[n][k]   (X: [4096][1024], W: [1024][1024])
// xf32: X is fp32 (else bf16 workspace). yf32: write fp32 (else bf16).
// mode 1: interleaved-pair RoPE per 64-wide head in the epilogue.
// Tile: 64(m) x 64(n), 4 waves; wave w computes rows w*16..w*16+15, all 64 cols.
// ---------------------------------------------------------------------------
__global__ __launch_bounds__(256) void gemm_nt(
    const void* __restrict__ Xv, const float* __restrict__ W,
    void* __restrict__ Yv, int xf32, int yf32, int mode)
{
    __shared__ u16 As[64 * LSTR];
    __shared__ u16 Bs[64 * LSTR];

    const int tid  = threadIdx.x;
    const int wave = tid >> 6;
    const int lane = tid & 63;
    const int quad = lane >> 4;
    const int l16  = lane & 15;
    const int m0 = blockIdx.y * 64;
    const int n0 = blockIdx.x * 64;
    const int srow = tid >> 2;           // 0..63
    const int cb   = (tid & 3) << 4;     // 0,16,32,48

    float4v acc[4];
#pragma unroll
    for (int i = 0; i < 4; i++) acc[i] = (float4v){0.f, 0.f, 0.f, 0.f};

    for (int kb = 0; kb < 1024; kb += 64) {
        __syncthreads();
        // ---- stage A: 16 elements of row (m0+srow), cols kb+cb..+15 ----
        {
            u16 t[16];
            if (xf32) {
                const float* Xf = reinterpret_cast<const float*>(Xv);
                const float4* g = reinterpret_cast<const float4*>(Xf + (size_t)(m0 + srow) * 1024 + kb + cb);
                float4 f0 = g[0], f1 = g[1], f2 = g[2], f3 = g[3];
                t[0]=f2b(f0.x); t[1]=f2b(f0.y); t[2]=f2b(f0.z); t[3]=f2b(f0.w);
                t[4]=f2b(f1.x); t[5]=f2b(f1.y); t[6]=f2b(f1.z); t[7]=f2b(f1.w);
                t[8]=f2b(f2.x); t[9]=f2b(f2.y); t[10]=f2b(f2.z); t[11]=f2b(f2.w);
                t[12]=f2b(f3.x); t[13]=f2b(f3.y); t[14]=f2b(f3.z); t[15]=f2b(f3.w);
            } else {
                const u16* Xb = reinterpret_cast<const u16*>(Xv);
                const int4* g = reinterpret_cast<const int4*>(Xb + (size_t)(m0 + srow) * 1024 + kb + cb);
                *reinterpret_cast<int4*>(&t[0]) = g[0];
                *reinterpret_cast<int4*>(&t[8]) = g[1];
            }
            *reinterpret_cast<int4*>(&As[srow * LSTR + cb])     = *reinterpret_cast<int4*>(&t[0]);
            *reinterpret_cast<int4*>(&As[srow * LSTR + cb + 8]) = *reinterpret_cast<int4*>(&t[8]);
        }
        // ---- stage B: W is always fp32 ----
        {
            u16 t[16];
            const float4* g = reinterpret_cast<const float4*>(W + (size_t)(n0 + srow) * 1024 + kb + cb);
            float4 f0 = g[0], f1 = g[1], f2 = g[2], f3 = g[3];
            t[0]=f2b(f0.x); t[1]=f2b(f0.y); t[2]=f2b(f0.z); t[3]=f2b(f0.w);
            t[4]=f2b(f1.x); t[5]=f2b(f1.y); t[6]=f2b(f1.z); t[7]=f2b(f1.w);
            t[8]=f2b(f2.x); t[9]=f2b(f2.y); t[10]=f2b(f2.z); t[11]=f2b(f2.w);
            t[12]=f2b(f3.x); t[13]=f2b(f3.y); t[14]=f2b(f3.z); t[15]=f2b(f3.w);
            *reinterpret_cast<int4*>(&Bs[srow * LSTR + cb])     = *reinterpret_cast<int4*>(&t[0]);
            *reinterpret_cast<int4*>(&Bs[srow * LSTR + cb + 8]) = *reinterpret_cast<int4*>(&t[8]);
        }
        __syncthreads();

#pragma unroll
        for (int ks = 0; ks < 2; ks++) {
            short8 afrag = *reinterpret_cast<const short8*>(&As[(wave * 16 + l16) * LSTR + ks * 32 + quad * 8]);
#pragma unroll
            for (int nt = 0; nt < 4; nt++) {
                short8 bfrag = *reinterpret_cast<const short8*>(&Bs[(nt * 16 + l16) * LSTR + ks * 32 + quad * 8]);
                acc[nt] = __builtin_amdgcn_mfma_f32_16x16x32_bf16(afrag, bfrag, acc[nt], 0, 0, 0);
            }
        }
    }

    // epilogue: C/D layout col = l16 (+n-tile), row = quad*4 + r (+wave strip)
#pragma unroll
    for (int nt = 0; nt < 4; nt++) {
        const int col = n0 + nt * 16 + l16;
#pragma unroll
        for (int r = 0; r < 4; r++) {
            const int m = m0 + wave * 16 + quad * 4 + r;
            float v = acc[nt][r];
            if (mode) {
                const int s = m & 2047;          // position within sequence
                const int d = col & 63;          // within head
                const int i = d >> 1;            // pair index
                float freq = powf(10000.0f, -(float)(2 * i) * (1.0f / 64.0f));
                float ang  = (float)s * freq;
                float c, sn;
                sincosf(ang, &sn, &c);
                float partner = __shfl_xor(v, 1);
                v = (d & 1) ? fmaf(v, c,  partner * sn)    // odd:  x_o*c + x_e*s
                            : fmaf(v, c, -partner * sn);   // even: x_e*c - x_o*s
            }
            if (yf32) reinterpret_cast<float*>(Yv)[(size_t)m * 1024 + col] = v;
            else      reinterpret_cast<u16*>(Yv)[(size_t)m * 1024 + col] = f2b(v);
        }
    }
}

// ---------------------------------------------------------------------------
// Flash-style causal attention. Q,K,V,O: [B][S][H*64] bf16 (our workspace).
// Block = (b, h, 64-row q-tile), 4 waves; wave owns 16 q rows.
// O may ALIAS Q (no __restrict__): each block reads Q only from its own
// (b, q-tile, h) 64x64 region into registers at start, writes O to exactly
// that region at the end; regions disjoint across blocks.
// ---------------------------------------------------------------------------
__global__ __launch_bounds__(256) void attn_kernel(
    const u16* Q, const u16* __restrict__ K,
    const u16* __restrict__ V, u16* O)
{
    __shared__ u16 Ks[64 * LSTR];
    __shared__ u16 Vt[64 * LSTR];      // Vt[d][s]
    __shared__ u16 Ps[4 * 16 * LSTR];  // per-wave P (16 x 64)

    const int tid  = threadIdx.x;
    const int wave = tid >> 6;
    const int lane = tid & 63;
    const int quad = lane >> 4;
    const int l16  = lane & 15;
    const int qt = blockIdx.x;                 // q tile index (0..31)
    const int h  = blockIdx.y;
    const int b  = blockIdx.z;
    const int q0 = qt * 64;
    const size_t base = ((size_t)b * 2048) * 1024 + (size_t)h * 64;

    // Q fragments: A-layout, rows (q0 + wave*16 + l16), k = d
    short8 qfrag[2];
    {
        const size_t qrow = base + (size_t)(q0 + wave * 16 + l16) * 1024;
        qfrag[0] = *reinterpret_cast<const short8*>(Q + qrow + quad * 8);
        qfrag[1] = *reinterpret_cast<const short8*>(Q + qrow + 32 + quad * 8);
    }

    float4v oacc[4];
#pragma unroll
    for (int i = 0; i < 4; i++) oacc[i] = (float4v){0.f, 0.f, 0.f, 0.f};
    float mrow[4] = {MASKV, MASKV, MASKV, MASKV};
    float lrow[4] = {0.f, 0.f, 0.f, 0.f};

    u16* Pw = Ps + wave * 16 * LSTR;
    const int srow = tid >> 2;
    const int cb   = (tid & 3) << 4;

    for (int j = 0; j <= qt; j++) {
        __syncthreads();   // previous PV reads done before restaging
        {
            const int4* gK = reinterpret_cast<const int4*>(K + base + (size_t)(j * 64 + srow) * 1024 + cb);
            int4 k0 = gK[0], k1 = gK[1];
            *reinterpret_cast<int4*>(&Ks[srow * LSTR + cb])     = k0;
            *reinterpret_cast<int4*>(&Ks[srow * LSTR + cb + 8]) = k1;
            const int4* gV = reinterpret_cast<const int4*>(V + base + (size_t)(j * 64 + srow) * 1024 + cb);
            int4 v0 = gV[0], v1 = gV[1];
            const u16* vp0 = reinterpret_cast<const u16*>(&v0);
            const u16* vp1 = reinterpret_cast<const u16*>(&v1);
#pragma unroll
            for (int e = 0; e < 8; e++) Vt[(cb + e) * LSTR + srow] = vp0[e];
#pragma unroll
            for (int e = 0; e < 8; e++) Vt[(cb + 8 + e) * LSTR + srow] = vp1[e];
        }
        __syncthreads();

        // S = Q K^T (wave's 16 rows x 64 cols)
        float4v sacc[4];
#pragma unroll
        for (int i = 0; i < 4; i++) sacc[i] = (float4v){0.f, 0.f, 0.f, 0.f};
#pragma unroll
        for (int nt = 0; nt < 4; nt++) {
#pragma unroll
            for (int ks = 0; ks < 2; ks++) {
                short8 bfrag = *reinterpret_cast<const short8*>(&Ks[(nt * 16 + l16) * LSTR + ks * 32 + quad * 8]);
                sacc[nt] = __builtin_amdgcn_mfma_f32_16x16x32_bf16(qfrag[ks], bfrag, sacc[nt], 0, 0, 0);
            }
        }

        const bool diag = (j == qt);
#pragma unroll
        for (int r = 0; r < 4; r++) {
            const int qloc = wave * 16 + quad * 4 + r;   // q row within tile
            float sv[4];
            float rmax = MASKV;
#pragma unroll
            for (int nt = 0; nt < 4; nt++) {
                float s = sacc[nt][r] * 0.125f;          // 1/sqrt(64)
                if (diag && (nt * 16 + l16 > qloc)) s = MASKV;
                sv[nt] = s;
                rmax = fmaxf(rmax, s);
            }
#pragma unroll
            for (int msk = 1; msk < 16; msk <<= 1) rmax = fmaxf(rmax, __shfl_xor(rmax, msk));
            const float mnew  = fmaxf(mrow[r], rmax);
            const float alpha = __expf(fminf(fmaxf(mrow[r] - mnew, -80.0f), 0.0f));
            float rsum = 0.f;
#pragma unroll
            for (int nt = 0; nt < 4; nt++) {
                float p = __expf(fminf(fmaxf(sv[nt] - mnew, -80.0f), 0.0f));  // masked -> ~0
                rsum += p;
                Pw[(quad * 4 + r) * LSTR + nt * 16 + l16] = f2b(p);
            }
#pragma unroll
            for (int msk = 1; msk < 16; msk <<= 1) rsum += __shfl_xor(rsum, msk);
            lrow[r] = lrow[r] * alpha + rsum;
            mrow[r] = mnew;
#pragma unroll
            for (int dt = 0; dt < 4; dt++) oacc[dt][r] *= alpha;
        }
        __syncthreads();   // P visibility before MFMA reads

        // O += P V
#pragma unroll
        for (int ks = 0; ks < 2; ks++) {
            short8 pfrag = *reinterpret_cast<const short8*>(&Pw[l16 * LSTR + ks * 32 + quad * 8]);
#pragma unroll
            for (int dt = 0; dt < 4; dt++) {
                short8 vfrag = *reinterpret_cast<const short8*>(&Vt[(dt * 16 + l16) * LSTR + ks * 32 + quad * 8]);
                oacc[dt] = __builtin_amdgcn_mfma_f32_16x16x32_bf16(pfrag, vfrag, oacc[dt], 0, 0, 0);
            }
        }
    }

    // epilogue: normalize by l, write [B][S][H*64] bf16
#pragma unroll
    for (int r = 0; r < 4; r++) {
        const float inv = 1.0f / fmaxf(lrow[r], 1e-30f);
        const int qg = q0 + wave * 16 + quad * 4 + r;
        const size_t orow = ((size_t)b * 2048 + qg) * 1024 + (size_t)h * 64;
#pragma unroll
        for (int dt = 0; dt < 4; dt++) {
            O[orow + dt * 16 + l16] = f2b(oacc[dt][r] * inv);
        }
    }
}

// ---------------------------------------------------------------------------
extern "C" void kernel_launch(void* const* d_in, const int* in_sizes, int n_in,
                              void* d_out, int out_size, void* d_ws, size_t ws_size,
                              hipStream_t stream) {
    (void)in_sizes; (void)n_in; (void)out_size; (void)ws_size;
    const float* x  = (const float*)d_in[0];
    const float* wq = (const float*)d_in[1];
    const float* wk = (const float*)d_in[2];
    const float* wv = (const float*)d_in[3];
    const float* wo = (const float*)d_in[4];

    const size_t MN = (size_t)4096 * 1024;   // 4M elements per [B,S,D] buffer
    u16* qbuf = (u16*)d_ws;                  // doubles as attention-output buf
    u16* kbuf = qbuf + MN;
    u16* vbuf = kbuf + MN;                   // total ws use: 24 MB

    dim3 gg(16, 64);     // n-tiles x m-tiles
    dim3 bb(256);
    gemm_nt<<<gg, bb, 0, stream>>>(x, wq, qbuf, 1, 0, 1);
    gemm_nt<<<gg, bb, 0, stream>>>(x, wk, kbuf, 1, 0, 1);
    gemm_nt<<<gg, bb, 0, stream>>>(x, wv, vbuf, 1, 0, 0);
    attn_kernel<<<dim3(32, 16, 2), bb, 0, stream>>>(qbuf, kbuf, vbuf, qbuf);  // O aliases Q (safe)
    gemm_nt<<<gg, bb, 0, stream>>>(qbuf, wo, d_out, 0, 1, 0);                 // fp32 out
}

// Round 7
// 257.813 us; speedup vs baseline: 1.4026x; 1.4026x over previous
//
#include <hip/hip_runtime.h>

// MHA forward, B=2, S=2048, D=1024, H=16, Dk=64, causal, RoPE.
// fp32 I/O (confirmed R4/R5); internal bf16 MFMA 16x16x32, fp32 accum.
// R7 = R6 structure with HIP-correct device math (exp2f/sincosf; the CUDA
// __exp2f/__sincosf spellings don't exist on HIP and broke the compile).

typedef unsigned short u16;
typedef __attribute__((ext_vector_type(8))) short short8;   // 8 bf16 = 4 VGPRs
typedef __attribute__((ext_vector_type(4))) float float4v;  // MFMA C/D

#define LSTR 72   // LDS row stride (u16): 144B rows -> 16B-aligned b128, 2-way banks

__device__ __forceinline__ u16 f2b(float f) {
    union { float f; unsigned int i; } t; t.f = f;
    unsigned int r = t.i + 0x7fffu + ((t.i >> 16) & 1u);   // RNE
    return (u16)(r >> 16);
}

// ---------------- fp32 -> bf16 converters (run once per launch) ------------
__global__ __launch_bounds__(256) void cvt1(const float4* __restrict__ s, u16* __restrict__ d) {
    const int i = blockIdx.x * 256 + threadIdx.x;
    float4 a = s[2 * i], b = s[2 * i + 1];
    u16 t[8] = {f2b(a.x), f2b(a.y), f2b(a.z), f2b(a.w), f2b(b.x), f2b(b.y), f2b(b.z), f2b(b.w)};
    reinterpret_cast<int4*>(d)[i] = *reinterpret_cast<int4*>(t);
}
__global__ __launch_bounds__(256) void cvt4(const float4* s0, const float4* s1,
                                            const float4* s2, const float4* s3,
                                            u16* d0, u16* d1, u16* d2, u16* d3) {
    const float4* s; u16* d;
    switch (blockIdx.y) {
        case 0:  s = s0; d = d0; break;
        case 1:  s = s1; d = d1; break;
        case 2:  s = s2; d = d2; break;
        default: s = s3; d = d3; break;
    }
    const int i = blockIdx.x * 256 + threadIdx.x;
    float4 a = s[2 * i], b = s[2 * i + 1];
    u16 t[8] = {f2b(a.x), f2b(a.y), f2b(a.z), f2b(a.w), f2b(b.x), f2b(b.y), f2b(b.z), f2b(b.w)};
    reinterpret_cast<int4*>(d)[i] = *reinterpret_cast<int4*>(t);
}

// ---------------------------------------------------------------------------
// Y[m][n] = sum_k X[m][k] * W[n][k], X:[4096][1024] bf16, W:[1024][1024] bf16.
// Tile 128(m) x 64(n) x 64(k); 4 waves, wave owns 32 m-rows (2 strips).
// rope: interleaved-pair RoPE per 64-wide head in epilogue. yf32: fp32 out.
// ---------------------------------------------------------------------------
__global__ __launch_bounds__(256) void gemm_nt(
    const u16* __restrict__ X, const u16* __restrict__ Wb,
    void* __restrict__ Yv, int yf32, int rope)
{
    __shared__ u16 As[128 * LSTR];
    __shared__ u16 Bs[64 * LSTR];

    const int tid  = threadIdx.x;
    const int wave = tid >> 6;
    const int lane = tid & 63;
    const int quad = lane >> 4;
    const int l16  = lane & 15;
    const int m0 = blockIdx.y * 128;
    const int n0 = blockIdx.x * 64;
    const int srowA = tid >> 1, cbA = (tid & 1) * 32;   // A: 128 rows, 32 elem/thread
    const int srowB = tid >> 2, cbB = (tid & 3) * 16;   // B: 64 rows, 16 elem/thread

    float4v acc[2][4];
#pragma unroll
    for (int mt = 0; mt < 2; mt++)
#pragma unroll
        for (int nt = 0; nt < 4; nt++) acc[mt][nt] = (float4v){0.f, 0.f, 0.f, 0.f};

    for (int kb = 0; kb < 1024; kb += 64) {
        __syncthreads();
        {
            const int4* gA = reinterpret_cast<const int4*>(X + (size_t)(m0 + srowA) * 1024 + kb + cbA);
            int4 a0 = gA[0], a1 = gA[1], a2 = gA[2], a3 = gA[3];
            *reinterpret_cast<int4*>(&As[srowA * LSTR + cbA])      = a0;
            *reinterpret_cast<int4*>(&As[srowA * LSTR + cbA + 8])  = a1;
            *reinterpret_cast<int4*>(&As[srowA * LSTR + cbA + 16]) = a2;
            *reinterpret_cast<int4*>(&As[srowA * LSTR + cbA + 24]) = a3;
            const int4* gB = reinterpret_cast<const int4*>(Wb + (size_t)(n0 + srowB) * 1024 + kb + cbB);
            int4 b0 = gB[0], b1 = gB[1];
            *reinterpret_cast<int4*>(&Bs[srowB * LSTR + cbB])     = b0;
            *reinterpret_cast<int4*>(&Bs[srowB * LSTR + cbB + 8]) = b1;
        }
        __syncthreads();

#pragma unroll
        for (int ks = 0; ks < 2; ks++) {
            short8 af[2], bf[4];
#pragma unroll
            for (int mt = 0; mt < 2; mt++)
                af[mt] = *reinterpret_cast<const short8*>(&As[(wave * 32 + mt * 16 + l16) * LSTR + ks * 32 + quad * 8]);
#pragma unroll
            for (int nt = 0; nt < 4; nt++)
                bf[nt] = *reinterpret_cast<const short8*>(&Bs[(nt * 16 + l16) * LSTR + ks * 32 + quad * 8]);
#pragma unroll
            for (int mt = 0; mt < 2; mt++)
#pragma unroll
                for (int nt = 0; nt < 4; nt++)
                    acc[mt][nt] = __builtin_amdgcn_mfma_f32_16x16x32_bf16(af[mt], bf[nt], acc[mt][nt], 0, 0, 0);
        }
    }

    // epilogue: C/D col = l16 (+tiles), row = quad*4 + r (+strips)
#pragma unroll
    for (int nt = 0; nt < 4; nt++) {
        const int col = n0 + nt * 16 + l16;
        float freq = 0.f;
        if (rope) {
            const int fi = (nt * 16 + l16) >> 1;             // pair index in head
            freq = exp2f((float)fi * -0.4152410118609203f);  // -log2(10000)/32
        }
#pragma unroll
        for (int mt = 0; mt < 2; mt++)
#pragma unroll
            for (int r = 0; r < 4; r++) {
                const int row = m0 + wave * 32 + mt * 16 + quad * 4 + r;
                float v = acc[mt][nt][r];
                if (rope) {
                    const float ang = (float)(row & 2047) * freq;   // pos in sequence
                    float sn, cs; sincosf(ang, &sn, &cs);
                    const float partner = __shfl_xor(v, 1);
                    v = (l16 & 1) ? fmaf(v, cs,  partner * sn)
                                  : fmaf(v, cs, -partner * sn);
                }
                if (yf32) reinterpret_cast<float*>(Yv)[(size_t)row * 1024 + col] = v;
                else      reinterpret_cast<u16*>(Yv)[(size_t)row * 1024 + col] = f2b(v);
            }
    }
}

// ---------------------------------------------------------------------------
// Flash causal attention, paired q-tiles. Block = (pair x, h, b): processes
// q-tiles qtA=x and qtB=31-x (uniform 33 strip-computes/block). KV staged once
// per j-tile for both sets; K/V MFMA fragments cached in regs per tile.
// Vt uses XOR swizzle: V[s][d] at Vt[d*LSTR + (s ^ ((d>>4)<<4))] -> staging
// writes spread over all 32 banks (2-way), reads stay ds_read_b128.
// O aliases Q: block reads Q only from its own q-tile rows (into regs, up
// front) and writes O to exactly those rows at the end.
// ---------------------------------------------------------------------------
__global__ __launch_bounds__(256) void attn_kernel(
    const u16* Q, const u16* __restrict__ K,
    const u16* __restrict__ V, u16* O)
{
    __shared__ u16 Ks[64 * LSTR];
    __shared__ u16 Vt[64 * LSTR];
    __shared__ u16 Ps[4 * 16 * LSTR];

    const int tid  = threadIdx.x;
    const int wave = tid >> 6;
    const int lane = tid & 63;
    const int quad = lane >> 4;
    const int l16  = lane & 15;
    const int qtA = blockIdx.x;          // 0..15
    const int qtB = 31 - qtA;            // 31..16
    const int h = blockIdx.y, b = blockIdx.z;
    const size_t base = ((size_t)b * 2048) * 1024 + (size_t)h * 64;

    // Q fragments (A-layout) for both sets
    short8 qfA[2], qfB[2];
    {
        const size_t ra = base + (size_t)(qtA * 64 + wave * 16 + l16) * 1024;
        qfA[0] = *reinterpret_cast<const short8*>(Q + ra + quad * 8);
        qfA[1] = *reinterpret_cast<const short8*>(Q + ra + 32 + quad * 8);
        const size_t rb = base + (size_t)(qtB * 64 + wave * 16 + l16) * 1024;
        qfB[0] = *reinterpret_cast<const short8*>(Q + rb + quad * 8);
        qfB[1] = *reinterpret_cast<const short8*>(Q + rb + 32 + quad * 8);
    }

    float4v oA[4], oB[4];
#pragma unroll
    for (int i = 0; i < 4; i++) { oA[i] = (float4v){0.f,0.f,0.f,0.f}; oB[i] = (float4v){0.f,0.f,0.f,0.f}; }
    float mA[4] = {-1e30f,-1e30f,-1e30f,-1e30f}, lA[4] = {0.f,0.f,0.f,0.f};
    float mB[4] = {-1e30f,-1e30f,-1e30f,-1e30f}, lB[4] = {0.f,0.f,0.f,0.f};

    u16* Pw = Ps + wave * 16 * LSTR;
    const int srow = tid >> 2;             // 0..63 (s row of staged tile)
    const int cb   = (tid & 3) << 4;       // 0,16,32,48 (d base)
    const int sxw  = srow ^ cb;            // Vt swizzled s (cb == (d>>4)<<4 for e<16)

    // register prefetch of tile j=0
    const u16* Kp = K + base + (size_t)srow * 1024 + cb;
    const u16* Vp = V + base + (size_t)srow * 1024 + cb;
    int4 kr0 = *reinterpret_cast<const int4*>(Kp), kr1 = *reinterpret_cast<const int4*>(Kp + 8);
    int4 vr0 = *reinterpret_cast<const int4*>(Vp), vr1 = *reinterpret_cast<const int4*>(Vp + 8);

    short8 kf[4][2], vf[4][2];

    auto proc = [&](const short8 (&qf)[2], float4v (&oc)[4], float (&mr)[4], float (&lr)[4], bool diag) {
        float4v sacc[4];
#pragma unroll
        for (int nt = 0; nt < 4; nt++) {
            sacc[nt] = (float4v){0.f, 0.f, 0.f, 0.f};
#pragma unroll
            for (int ks = 0; ks < 2; ks++)
                sacc[nt] = __builtin_amdgcn_mfma_f32_16x16x32_bf16(qf[ks], kf[nt][ks], sacc[nt], 0, 0, 0);
        }
#pragma unroll
        for (int r = 0; r < 4; r++) {
            const int qloc = wave * 16 + quad * 4 + r;
            float sv[4]; float rmax = -1e30f;
#pragma unroll
            for (int nt = 0; nt < 4; nt++) {
                float s = sacc[nt][r] * 0.125f;                    // 1/sqrt(64)
                if (diag && (nt * 16 + l16 > qloc)) s = -1e30f;
                sv[nt] = s; rmax = fmaxf(rmax, s);
            }
#pragma unroll
            for (int msk = 1; msk < 16; msk <<= 1) rmax = fmaxf(rmax, __shfl_xor(rmax, msk));
            const float mnew  = fmaxf(mr[r], rmax);
            const float alpha = __expf(fminf(fmaxf(mr[r] - mnew, -80.f), 0.f));
            float rsum = 0.f;
#pragma unroll
            for (int nt = 0; nt < 4; nt++) {
                float p = __expf(fminf(fmaxf(sv[nt] - mnew, -80.f), 0.f));
                rsum += p;
                Pw[(quad * 4 + r) * LSTR + nt * 16 + l16] = f2b(p);
            }
#pragma unroll
            for (int msk = 1; msk < 16; msk <<= 1) rsum += __shfl_xor(rsum, msk);
            lr[r] = lr[r] * alpha + rsum;
            mr[r] = mnew;
#pragma unroll
            for (int dt = 0; dt < 4; dt++) oc[dt][r] *= alpha;
        }
        __builtin_amdgcn_wave_barrier();   // P write -> read: wave-local, DS in-order
#pragma unroll
        for (int ks = 0; ks < 2; ks++) {
            short8 pf = *reinterpret_cast<const short8*>(&Pw[l16 * LSTR + ks * 32 + quad * 8]);
#pragma unroll
            for (int dt = 0; dt < 4; dt++)
                oc[dt] = __builtin_amdgcn_mfma_f32_16x16x32_bf16(pf, vf[dt][ks], oc[dt], 0, 0, 0);
        }
        __builtin_amdgcn_wave_barrier();
    };

    for (int j = 0; j <= qtB; j++) {
        __syncthreads();   // all waves done reading previous tile
        {
            *reinterpret_cast<int4*>(&Ks[srow * LSTR + cb])     = kr0;
            *reinterpret_cast<int4*>(&Ks[srow * LSTR + cb + 8]) = kr1;
            const u16* a = reinterpret_cast<const u16*>(&vr0);
            const u16* c = reinterpret_cast<const u16*>(&vr1);
#pragma unroll
            for (int e = 0; e < 8; e++) Vt[(cb + e) * LSTR + sxw] = a[e];
#pragma unroll
            for (int e = 0; e < 8; e++) Vt[(cb + 8 + e) * LSTR + sxw] = c[e];
        }
        __syncthreads();
        if (j < qtB) {     // prefetch next tile; latency overlaps compute below
            Kp += 65536; Vp += 65536;
            kr0 = *reinterpret_cast<const int4*>(Kp); kr1 = *reinterpret_cast<const int4*>(Kp + 8);
            vr0 = *reinterpret_cast<const int4*>(Vp); vr1 = *reinterpret_cast<const int4*>(Vp + 8);
        }
        // cache K/V fragments once for both q-sets
#pragma unroll
        for (int nt = 0; nt < 4; nt++)
#pragma unroll
            for (int ks = 0; ks < 2; ks++) {
                kf[nt][ks] = *reinterpret_cast<const short8*>(&Ks[(nt * 16 + l16) * LSTR + ks * 32 + quad * 8]);
                vf[nt][ks] = *reinterpret_cast<const short8*>(&Vt[(nt * 16 + l16) * LSTR + ((ks * 32 + quad * 8) ^ (nt << 4))]);
            }
        if (j <= qtA) proc(qfA, oA, mA, lA, j == qtA);
        proc(qfB, oB, mB, lB, j == qtB);
    }

    // epilogue: normalize, write both q-sets
#pragma unroll
    for (int r = 0; r < 4; r++) {
        const float invA = 1.0f / lA[r];
        const float invB = 1.0f / lB[r];
        const int rloc = wave * 16 + quad * 4 + r;
        const size_t rowA = base + (size_t)(qtA * 64 + rloc) * 1024;
        const size_t rowB = base + (size_t)(qtB * 64 + rloc) * 1024;
#pragma unroll
        for (int dt = 0; dt < 4; dt++) {
            O[rowA + dt * 16 + l16] = f2b(oA[dt][r] * invA);
            O[rowB + dt * 16 + l16] = f2b(oB[dt][r] * invB);
        }
    }
}

// ---------------------------------------------------------------------------
extern "C" void kernel_launch(void* const* d_in, const int* in_sizes, int n_in,
                              void* d_out, int out_size, void* d_ws, size_t ws_size,
                              hipStream_t stream) {
    (void)in_sizes; (void)n_in; (void)out_size; (void)ws_size;
    const float* x  = (const float*)d_in[0];
    const float* wq = (const float*)d_in[1];
    const float* wk = (const float*)d_in[2];
    const float* wv = (const float*)d_in[3];
    const float* wo = (const float*)d_in[4];

    const size_t MN = (size_t)4096 * 1024;   // x / q / k / v element count
    const size_t WN = (size_t)1024 * 1024;   // weight element count

    // bf16 temporaries: x + 3 weights live in d_out (16MB, fully overwritten
    // by the final fp32 GEMM write); wo_b + q/k/v live in ws (26MB).
    u16* xb  = (u16*)d_out;
    u16* wqb = xb + MN;
    u16* wkb = wqb + WN;
    u16* wvb = wkb + WN;                     // ends at 14MB of 16MB
    u16* qbuf = (u16*)d_ws;                  // also attention output
    u16* kbuf = qbuf + MN;
    u16* vbuf = kbuf + MN;
    u16* wob  = vbuf + MN;                   // ws total: 26MB

    cvt1<<<2048, 256, 0, stream>>>((const float4*)x, xb);
    cvt4<<<dim3(512, 4), 256, 0, stream>>>((const float4*)wq, (const float4*)wk,
                                           (const float4*)wv, (const float4*)wo,
                                           wqb, wkb, wvb, wob);
    dim3 gg(16, 32);   // n-tiles(64) x m-tiles(128)
    gemm_nt<<<gg, 256, 0, stream>>>(xb, wqb, qbuf, 0, 1);
    gemm_nt<<<gg, 256, 0, stream>>>(xb, wkb, kbuf, 0, 1);
    gemm_nt<<<gg, 256, 0, stream>>>(xb, wvb, vbuf, 0, 0);
    attn_kernel<<<dim3(16, 16, 2), 256, 0, stream>>>(qbuf, kbuf, vbuf, qbuf);
    gemm_nt<<<gg, 256, 0, stream>>>(qbuf, wob, d_out, 1, 0);
}

// Round 8
// 228.735 us; speedup vs baseline: 1.5809x; 1.1271x over previous
//
#include <hip/hip_runtime.h>

// MHA forward, B=2, S=2048, D=1024, H=16, Dk=64, causal, RoPE. fp32 I/O.
// Internal bf16 MFMA 16x16x32, fp32 accum.
// R8: (a) attn: unnormalized softmax (scores bounded; fp32 additive row-sum,
// one end reduction) + 0.125*log2e folded into q at GEMM -> bare exp2f;
// (b) K fragments read direct from global (natural B-layout), prefetched —
// no K LDS staging; (c) QKV fused into one 128x128-tile GEMM over wcat,
// software-pipelined staging; out-proj reuses the kernel with fp32 out;
// (d) single fused cvt kernel. 4 launches total.

typedef unsigned short u16;
typedef __attribute__((ext_vector_type(8))) short short8;   // 8 bf16 = 4 VGPRs
typedef __attribute__((ext_vector_type(4))) float float4v;  // MFMA C/D

#define LSTR 72   // LDS row stride (u16): 2-way bank alias (free per m136)
#define QSCL 0.18033688011112042f   // 0.125 * log2(e)

__device__ __forceinline__ u16 f2b(float f) {
    union { float f; unsigned int i; } t; t.f = f;
    unsigned int r = t.i + 0x7fffu + ((t.i >> 16) & 1u);   // RNE
    return (u16)(r >> 16);
}

// ---------------- fused fp32 -> bf16 converter (1M threads x 8 elem) -------
__global__ __launch_bounds__(256) void cvt_all(
    const float4* __restrict__ x,  const float4* __restrict__ wq,
    const float4* __restrict__ wk, const float4* __restrict__ wv,
    const float4* __restrict__ wo,
    u16* __restrict__ xb, u16* __restrict__ wcat, u16* __restrict__ wob)
{
    const int i = blockIdx.x * 256 + threadIdx.x;
    const float4* s; u16* d; int off;
    if (i < 524288) { s = x; d = xb; off = i; }          // 4M elems of x
    else {
        const int widx = i - 524288;                     // 4M weight elems
        const int w = widx >> 17, o = widx & 131071;
        switch (w) {
            case 0:  s = wq; d = wcat;              break;
            case 1:  s = wk; d = wcat + (1 << 20);  break;
            case 2:  s = wv; d = wcat + (2 << 20);  break;
            default: s = wo; d = wob;               break;
        }
        off = o;
    }
    float4 a = s[2 * off], b = s[2 * off + 1];
    u16 t[8] = {f2b(a.x), f2b(a.y), f2b(a.z), f2b(a.w),
                f2b(b.x), f2b(b.y), f2b(b.z), f2b(b.w)};
    reinterpret_cast<int4*>(d)[off] = *reinterpret_cast<int4*>(t);
}

// ---------------------------------------------------------------------------
// Y[m][n] = sum_k X[m][k] * W[n][k]; X:[4096][1024] bf16, W:[N][1024] bf16.
// Tile 128x128x64; 4 waves in 2x2, each 64x64 (4x4 MFMA acc).
// rope=1 (QKV): route cols to Yq/Yk/Yv by n>>10; RoPE on q,k; q scaled QSCL.
// rope=0: fp32 out to Yf.
// ---------------------------------------------------------------------------
__global__ __launch_bounds__(256) void gemm128(
    const u16* __restrict__ X, const u16* __restrict__ Wb,
    u16* __restrict__ Yq, u16* __restrict__ Yk, u16* __restrict__ Yv,
    float* __restrict__ Yf, int rope)
{
    __shared__ u16 As[128 * LSTR];
    __shared__ u16 Bs[128 * LSTR];

    const int tid  = threadIdx.x;
    const int wave = tid >> 6;
    const int lane = tid & 63;
    const int quad = lane >> 4;
    const int l16  = lane & 15;
    const int wm = (wave >> 1) * 64, wn = (wave & 1) * 64;
    const int m0 = blockIdx.y * 128, n0 = blockIdx.x * 128;
    const int srow = tid >> 1;            // 0..127
    const int cb   = (tid & 1) * 32;      // 0 or 32 (u16)

    float4v acc[4][4];
#pragma unroll
    for (int mt = 0; mt < 4; mt++)
#pragma unroll
        for (int nt = 0; nt < 4; nt++) acc[mt][nt] = (float4v){0.f, 0.f, 0.f, 0.f};

    int4 a0, a1, a2, a3, b0, b1, b2, b3;
    {
        const int4* gA = reinterpret_cast<const int4*>(X + (size_t)(m0 + srow) * 1024 + cb);
        a0 = gA[0]; a1 = gA[1]; a2 = gA[2]; a3 = gA[3];
        const int4* gB = reinterpret_cast<const int4*>(Wb + (size_t)(n0 + srow) * 1024 + cb);
        b0 = gB[0]; b1 = gB[1]; b2 = gB[2]; b3 = gB[3];
    }

    for (int kb = 0; kb < 1024; kb += 64) {
        __syncthreads();
        *reinterpret_cast<int4*>(&As[srow * LSTR + cb])      = a0;
        *reinterpret_cast<int4*>(&As[srow * LSTR + cb + 8])  = a1;
        *reinterpret_cast<int4*>(&As[srow * LSTR + cb + 16]) = a2;
        *reinterpret_cast<int4*>(&As[srow * LSTR + cb + 24]) = a3;
        *reinterpret_cast<int4*>(&Bs[srow * LSTR + cb])      = b0;
        *reinterpret_cast<int4*>(&Bs[srow * LSTR + cb + 8])  = b1;
        *reinterpret_cast<int4*>(&Bs[srow * LSTR + cb + 16]) = b2;
        *reinterpret_cast<int4*>(&Bs[srow * LSTR + cb + 24]) = b3;
        __syncthreads();
        if (kb + 64 < 1024) {   // prefetch next K-slab; in flight during MFMA
            const int4* gA = reinterpret_cast<const int4*>(X + (size_t)(m0 + srow) * 1024 + kb + 64 + cb);
            a0 = gA[0]; a1 = gA[1]; a2 = gA[2]; a3 = gA[3];
            const int4* gB = reinterpret_cast<const int4*>(Wb + (size_t)(n0 + srow) * 1024 + kb + 64 + cb);
            b0 = gB[0]; b1 = gB[1]; b2 = gB[2]; b3 = gB[3];
        }
#pragma unroll
        for (int ks = 0; ks < 2; ks++) {
            short8 af[4], bf[4];
#pragma unroll
            for (int t = 0; t < 4; t++) {
                af[t] = *reinterpret_cast<const short8*>(&As[(wm + t * 16 + l16) * LSTR + ks * 32 + quad * 8]);
                bf[t] = *reinterpret_cast<const short8*>(&Bs[(wn + t * 16 + l16) * LSTR + ks * 32 + quad * 8]);
            }
#pragma unroll
            for (int mt = 0; mt < 4; mt++)
#pragma unroll
                for (int nt = 0; nt < 4; nt++)
                    acc[mt][nt] = __builtin_amdgcn_mfma_f32_16x16x32_bf16(af[mt], bf[nt], acc[mt][nt], 0, 0, 0);
        }
    }

    if (rope) {
#pragma unroll
        for (int nt = 0; nt < 4; nt++) {
            const int cg = n0 + wn + nt * 16 + l16;       // global col 0..3071
            const int buf = cg >> 10;                     // 0=q 1=k 2=v (uniform/block)
            const int c = cg & 1023;
            u16* dst = (buf == 0) ? Yq : ((buf == 1) ? Yk : Yv);
            const bool rp = (buf < 2);
            const float scl = (buf == 0) ? QSCL : 1.0f;
            float freq = 0.f;
            if (rp) freq = exp2f((float)((cg & 63) >> 1) * -0.4152410118609203f);  // -log2(1e4)/32
#pragma unroll
            for (int mt = 0; mt < 4; mt++)
#pragma unroll
                for (int r = 0; r < 4; r++) {
                    const int row = m0 + wm + mt * 16 + quad * 4 + r;
                    float v = acc[mt][nt][r];
                    if (rp) {
                        float sn, cs; sincosf((float)(row & 2047) * freq, &sn, &cs);
                        const float partner = __shfl_xor(v, 1);
                        v = (l16 & 1) ? fmaf(v, cs,  partner * sn)
                                      : fmaf(v, cs, -partner * sn);
                    }
                    dst[(size_t)row * 1024 + c] = f2b(v * scl);
                }
        }
    } else {
#pragma unroll
        for (int nt = 0; nt < 4; nt++) {
            const int col = n0 + wn + nt * 16 + l16;
#pragma unroll
            for (int mt = 0; mt < 4; mt++)
#pragma unroll
                for (int r = 0; r < 4; r++) {
                    const int row = m0 + wm + mt * 16 + quad * 4 + r;
                    Yf[(size_t)row * 1024 + col] = acc[mt][nt][r];
                }
        }
    }
}

// ---------------------------------------------------------------------------
// Flash causal attention, paired q-tiles (qtA, 31-qtA), unnormalized softmax.
// q pre-scaled by 0.125*log2e -> p = exp2f(s). K frags direct from global
// (B-operand natural layout), register-prefetched one tile ahead. V staged
// to LDS XOR-swizzled transpose. O aliases Q (block-disjoint regions).
// ---------------------------------------------------------------------------
__global__ __launch_bounds__(256, 2) void attn_kernel(
    const u16* Q, const u16* __restrict__ K,
    const u16* __restrict__ V, u16* O)
{
    __shared__ u16 Vt[64 * LSTR];
    __shared__ u16 Ps[4 * 16 * LSTR];

    const int tid  = threadIdx.x;
    const int wave = tid >> 6;
    const int lane = tid & 63;
    const int quad = lane >> 4;
    const int l16  = lane & 15;
    const int qtA = blockIdx.x;          // 0..15
    const int qtB = 31 - qtA;            // 31..16
    const int h = blockIdx.y, b = blockIdx.z;
    const size_t base = ((size_t)b * 2048) * 1024 + (size_t)h * 64;

    short8 qfA[2], qfB[2];
    {
        const size_t ra = base + (size_t)(qtA * 64 + wave * 16 + l16) * 1024;
        qfA[0] = *reinterpret_cast<const short8*>(Q + ra + quad * 8);
        qfA[1] = *reinterpret_cast<const short8*>(Q + ra + 32 + quad * 8);
        const size_t rb = base + (size_t)(qtB * 64 + wave * 16 + l16) * 1024;
        qfB[0] = *reinterpret_cast<const short8*>(Q + rb + quad * 8);
        qfB[1] = *reinterpret_cast<const short8*>(Q + rb + 32 + quad * 8);
    }

    float4v oA[4], oB[4];
#pragma unroll
    for (int i = 0; i < 4; i++) { oA[i] = (float4v){0.f,0.f,0.f,0.f}; oB[i] = (float4v){0.f,0.f,0.f,0.f}; }
    float sA[4] = {0.f,0.f,0.f,0.f}, sB[4] = {0.f,0.f,0.f,0.f};

    u16* Pw = Ps + wave * 16 * LSTR;
    const int srow = tid >> 2;             // 0..63
    const int cb   = (tid & 3) << 4;       // 0,16,32,48
    const int sxw  = srow ^ cb;            // Vt swizzle

    // prefetch tile j=0: V slab + K fragments (natural B layout)
    const u16* Vp = V + base + (size_t)srow * 1024 + cb;
    const u16* kbase = K + base + (size_t)l16 * 1024 + quad * 8;
    int4 vr0 = *reinterpret_cast<const int4*>(Vp), vr1 = *reinterpret_cast<const int4*>(Vp + 8);
    short8 kn[4][2], kc[4][2], vf[4][2];
#pragma unroll
    for (int nt = 0; nt < 4; nt++)
#pragma unroll
        for (int ks = 0; ks < 2; ks++)
            kn[nt][ks] = *reinterpret_cast<const short8*>(kbase + (size_t)(nt * 16) * 1024 + ks * 32);

    auto proc = [&](const short8 (&qf)[2], float4v (&oc)[4], float (&sr)[4], bool diag) {
        float4v sacc[4];
#pragma unroll
        for (int nt = 0; nt < 4; nt++) {
            sacc[nt] = (float4v){0.f, 0.f, 0.f, 0.f};
#pragma unroll
            for (int ks = 0; ks < 2; ks++)
                sacc[nt] = __builtin_amdgcn_mfma_f32_16x16x32_bf16(qf[ks], kc[nt][ks], sacc[nt], 0, 0, 0);
        }
#pragma unroll
        for (int r = 0; r < 4; r++) {
            const int qloc = wave * 16 + quad * 4 + r;
#pragma unroll
            for (int nt = 0; nt < 4; nt++) {
                float s = sacc[nt][r];                       // already log2-domain
                if (diag && (nt * 16 + l16 > qloc)) s = -1e30f;
                const float p = exp2f(s);                    // masked -> 0
                sr[r] += p;
                Pw[(quad * 4 + r) * LSTR + nt * 16 + l16] = f2b(p);
            }
        }
        __builtin_amdgcn_wave_barrier();   // P write->read is wave-local
#pragma unroll
        for (int ks = 0; ks < 2; ks++) {
            short8 pf = *reinterpret_cast<const short8*>(&Pw[l16 * LSTR + ks * 32 + quad * 8]);
#pragma unroll
            for (int dt = 0; dt < 4; dt++)
                oc[dt] = __builtin_amdgcn_mfma_f32_16x16x32_bf16(pf, vf[dt][ks], oc[dt], 0, 0, 0);
        }
        __builtin_amdgcn_wave_barrier();
    };

    for (int j = 0; j <= qtB; j++) {
        __syncthreads();   // all waves done reading previous Vt
        {
            const u16* a = reinterpret_cast<const u16*>(&vr0);
            const u16* c = reinterpret_cast<const u16*>(&vr1);
#pragma unroll
            for (int e = 0; e < 8; e++) Vt[(cb + e) * LSTR + sxw] = a[e];
#pragma unroll
            for (int e = 0; e < 8; e++) Vt[(cb + 8 + e) * LSTR + sxw] = c[e];
        }
#pragma unroll
        for (int nt = 0; nt < 4; nt++)
#pragma unroll
            for (int ks = 0; ks < 2; ks++) kc[nt][ks] = kn[nt][ks];
        __syncthreads();
        if (j < qtB) {     // prefetch tile j+1; latency hidden by procs
            Vp += 65536;
            vr0 = *reinterpret_cast<const int4*>(Vp); vr1 = *reinterpret_cast<const int4*>(Vp + 8);
            const u16* kb2 = kbase + (size_t)(j + 1) * 65536;
#pragma unroll
            for (int nt = 0; nt < 4; nt++)
#pragma unroll
                for (int ks = 0; ks < 2; ks++)
                    kn[nt][ks] = *reinterpret_cast<const short8*>(kb2 + (size_t)(nt * 16) * 1024 + ks * 32);
        }
#pragma unroll
        for (int nt = 0; nt < 4; nt++)
#pragma unroll
            for (int ks = 0; ks < 2; ks++)
                vf[nt][ks] = *reinterpret_cast<const short8*>(&Vt[(nt * 16 + l16) * LSTR + ((ks * 32 + quad * 8) ^ (nt << 4))]);
        if (j <= qtA) proc(qfA, oA, sA, j == qtA);
        proc(qfB, oB, sB, j == qtB);
    }

    // epilogue: single cross-lane sum reduction, normalize, write
#pragma unroll
    for (int r = 0; r < 4; r++) {
        float la = sA[r], lb = sB[r];
#pragma unroll
        for (int msk = 1; msk < 16; msk <<= 1) { la += __shfl_xor(la, msk); lb += __shfl_xor(lb, msk); }
        const float invA = 1.0f / la, invB = 1.0f / lb;
        const int rloc = wave * 16 + quad * 4 + r;
        const size_t rowA = base + (size_t)(qtA * 64 + rloc) * 1024;
        const size_t rowB = base + (size_t)(qtB * 64 + rloc) * 1024;
#pragma unroll
        for (int dt = 0; dt < 4; dt++) {
            O[rowA + dt * 16 + l16] = f2b(oA[dt][r] * invA);
            O[rowB + dt * 16 + l16] = f2b(oB[dt][r] * invB);
        }
    }
}

// ---------------------------------------------------------------------------
extern "C" void kernel_launch(void* const* d_in, const int* in_sizes, int n_in,
                              void* d_out, int out_size, void* d_ws, size_t ws_size,
                              hipStream_t stream) {
    (void)in_sizes; (void)n_in; (void)out_size; (void)ws_size;
    const float* x  = (const float*)d_in[0];
    const float* wq = (const float*)d_in[1];
    const float* wk = (const float*)d_in[2];
    const float* wv = (const float*)d_in[3];
    const float* wo = (const float*)d_in[4];

    const size_t MN = (size_t)4096 * 1024;

    // d_out (16MB) hosts xb (8MB) + wcat (6MB) until the final fp32 write.
    u16* xb   = (u16*)d_out;
    u16* wcat = xb + MN;                    // [3072][1024] = wq|wk|wv rows
    // ws (26MB): q/k/v bf16 + wo bf16
    u16* qbuf = (u16*)d_ws;                 // also attention output
    u16* kbuf = qbuf + MN;
    u16* vbuf = kbuf + MN;
    u16* wob  = vbuf + MN;

    cvt_all<<<4096, 256, 0, stream>>>((const float4*)x, (const float4*)wq,
                                      (const float4*)wk, (const float4*)wv,
                                      (const float4*)wo, xb, wcat, wob);
    gemm128<<<dim3(24, 32), 256, 0, stream>>>(xb, wcat, qbuf, kbuf, vbuf, nullptr, 1);
    attn_kernel<<<dim3(16, 16, 2), 256, 0, stream>>>(qbuf, kbuf, vbuf, qbuf);
    gemm128<<<dim3(8, 32), 256, 0, stream>>>(qbuf, wob, nullptr, nullptr, nullptr, (float*)d_out, 0);
}